// Round 1
// baseline (871.304 us; speedup 1.0000x reference)
//
#include <hip/hip_runtime.h>

typedef unsigned short u16;
typedef unsigned int u32;
typedef short bf16x8 __attribute__((ext_vector_type(8)));
typedef float f4 __attribute__((ext_vector_type(4)));
typedef u16 u16x4 __attribute__((ext_vector_type(4)));
typedef u16 u16x8 __attribute__((ext_vector_type(8)));

#define CDIM 768
#define NPROJ 5376
#define KFF 3840   // combined K for final gemm: 768 (attn) + 3072 (mlp)
#define NTOK 16384

__device__ __forceinline__ u16 f2b(float f) {
    u32 u = __float_as_uint(f);
    u = (u + 0x7fffu + ((u >> 16) & 1u)) >> 16;   // RNE
    return (u16)u;
}
__device__ __forceinline__ float b2f(u16 h) {
    return __uint_as_float(((u32)h) << 16);
}
__device__ __forceinline__ float wsum64(float v) {
#pragma unroll
    for (int m = 32; m > 0; m >>= 1) v += __shfl_xor(v, m, 64);
    return v;
}
__device__ __forceinline__ void gl_lds16(const u16* g, u16* l) {
    __builtin_amdgcn_global_load_lds((__attribute__((address_space(1))) u32*)g,
                                     (__attribute__((address_space(3))) u32*)l,
                                     16, 0, 0);
}

// ---------------- transpose + fp32->bf16 cast: dst[c*dstride+doff+r] = src[r*Cc+c]
__global__ __launch_bounds__(256) void transpose_cast(const float* __restrict__ src,
                                                      u16* __restrict__ dst,
                                                      int R, int Cc, int dstride, int doff) {
    __shared__ float t[32][33];
    int c0 = blockIdx.x * 32, r0 = blockIdx.y * 32;
    int tx = threadIdx.x, ty = threadIdx.y;
#pragma unroll
    for (int i = 0; i < 32; i += 8) {
        int r = r0 + ty + i, c = c0 + tx;
        if (r < R && c < Cc) t[ty + i][tx] = src[(size_t)r * Cc + c];
    }
    __syncthreads();
#pragma unroll
    for (int i = 0; i < 32; i += 8) {
        int c = c0 + ty + i, r = r0 + tx;
        if (r < R && c < Cc) dst[(size_t)c * dstride + doff + r] = f2b(t[tx][ty + i]);
    }
}

// ---------------- LayerNorm over C=768, write bf16. 4 rows/block, one wave per row.
__global__ __launch_bounds__(256) void ln_rows(const float* __restrict__ x,
                                               const float* __restrict__ w,
                                               u16* __restrict__ xn) {
    int row = blockIdx.x * 4 + (threadIdx.x >> 6);
    int lane = threadIdx.x & 63;
    const f4* xr = (const f4*)(x + (size_t)row * CDIM);
    const f4* wr = (const f4*)w;
    f4 v[3];
    float s = 0.f, s2 = 0.f;
#pragma unroll
    for (int i = 0; i < 3; ++i) {
        v[i] = xr[lane + 64 * i];
#pragma unroll
        for (int j = 0; j < 4; ++j) { s += v[i][j]; s2 += v[i][j] * v[i][j]; }
    }
    s = wsum64(s); s2 = wsum64(s2);
    float mu = s * (1.f / 768.f);
    float var = s2 * (1.f / 768.f) - mu * mu;
    float rs = rsqrtf(var + 1e-5f);
    u16x4* xo = (u16x4*)(xn + (size_t)row * CDIM);
#pragma unroll
    for (int i = 0; i < 3; ++i) {
        f4 wv = wr[lane + 64 * i];
        u16x4 pk;
#pragma unroll
        for (int j = 0; j < 4; ++j) pk[j] = f2b((v[i][j] - mu) * rs * wv[j]);
        xo[lane + 64 * i] = pk;
    }
}

// ---------------- bf16 MFMA GEMM, A (M x K) row-major, B^T (N x K) row-major.
// 128x128 block tile, BK=32, 4 waves (2x2), 4x4 16x16x32 MFMA per wave.
// MODE 0: proj epilogue (+bqkv; cols<2304 -> qkv buf; else gelu -> A2 ff region)
// MODE 1: final epilogue (+bout+bmlp, out = x + gamma*acc)
template <int MODE>
__global__ __launch_bounds__(256) void gemm_bt(
    const u16* __restrict__ A, const u16* __restrict__ B, int M, int N, int K,
    const float* __restrict__ bias0, const float* __restrict__ bias1,
    const float* __restrict__ xres, const float* __restrict__ gamma,
    u16* __restrict__ oqkv, u16* __restrict__ off, float* __restrict__ ofin) {
    __shared__ u16 As[128 * 32];
    __shared__ u16 Bs[128 * 32];
    const int tid = threadIdx.x;
    const int wid = tid >> 6, lane = tid & 63;
    const int wm = wid >> 1, wn = wid & 1;
    const int quad = lane >> 4, l16 = lane & 15;
    const int m0 = blockIdx.y * 128, n0 = blockIdx.x * 128;

    f4 acc[4][4] = {};

    const int srow = tid >> 2;        // 0..63
    const int scol = (tid & 3) * 8;   // 16B chunk within a 64B row
    const u16* a0 = A + (size_t)(m0 + srow) * K + scol;
    const u16* a1 = a0 + (size_t)64 * K;
    const u16* b0 = B + (size_t)(n0 + srow) * K + scol;
    const u16* b1 = b0 + (size_t)64 * K;
    u16* as0 = As + (wid * 64) * 8;           // wave-uniform LDS bases
    u16* as1 = As + (256 + wid * 64) * 8;
    u16* bs0 = Bs + (wid * 64) * 8;
    u16* bs1 = Bs + (256 + wid * 64) * 8;

    for (int kt = 0; kt < K; kt += 32) {
        gl_lds16(a0 + kt, as0);
        gl_lds16(a1 + kt, as1);
        gl_lds16(b0 + kt, bs0);
        gl_lds16(b1 + kt, bs1);
        __syncthreads();
        bf16x8 af[4], bfv[4];
#pragma unroll
        for (int mi = 0; mi < 4; ++mi)
            af[mi] = *(const bf16x8*)(As + (wm * 64 + mi * 16 + l16) * 32 + quad * 8);
#pragma unroll
        for (int ni = 0; ni < 4; ++ni)
            bfv[ni] = *(const bf16x8*)(Bs + (wn * 64 + ni * 16 + l16) * 32 + quad * 8);
#pragma unroll
        for (int mi = 0; mi < 4; ++mi)
#pragma unroll
            for (int ni = 0; ni < 4; ++ni)
                acc[mi][ni] = __builtin_amdgcn_mfma_f32_16x16x32_bf16(af[mi], bfv[ni], acc[mi][ni], 0, 0, 0);
        __syncthreads();
    }

#pragma unroll
    for (int mi = 0; mi < 4; ++mi) {
#pragma unroll
        for (int ni = 0; ni < 4; ++ni) {
            const int col = n0 + wn * 64 + ni * 16 + l16;
            const int rowb = m0 + wm * 64 + mi * 16 + quad * 4;
            if (MODE == 0) {
                const float bc = bias0[col];
#pragma unroll
                for (int r = 0; r < 4; ++r) {
                    float vv = acc[mi][ni][r] + bc;
                    const int m = rowb + r;
                    if (col < 2304) {
                        oqkv[(size_t)m * 2304 + col] = f2b(vv);
                    } else {
                        float g = 0.5f * vv * (1.f + erff(vv * 0.70710678118654752f));
                        off[(size_t)m * KFF + 768 + (col - 2304)] = f2b(g);
                    }
                }
            } else {
                const float bc = bias0[col] + bias1[col];
                const float gm = gamma[col];
#pragma unroll
                for (int r = 0; r < 4; ++r) {
                    const int m = rowb + r;
                    float vv = acc[mi][ni][r] + bc;
                    ofin[(size_t)m * CDIM + col] = xres[(size_t)m * CDIM + col] + gm * vv;
                }
            }
        }
    }
}

// ---------------- per-head LN of q and k (64-elem rows), in place on bf16 qkv buffer.
// one block per token; each wave handles 6 of the 24 head-vectors.
__global__ __launch_bounds__(256) void qk_ln(u16* __restrict__ qkv,
                                             const float* __restrict__ qw,
                                             const float* __restrict__ kw) {
    const size_t m = blockIdx.x;
    const int w = threadIdx.x >> 6, lane = threadIdx.x & 63;
#pragma unroll
    for (int it = 0; it < 6; ++it) {
        const int h = w + 4 * it;   // 0..23
        const int isq = (h < 12);
        const int he = isq ? h : h - 12;
        u16* p = qkv + m * 2304 + (isq ? 0 : 768) + he * 64 + lane;
        const float wt = (isq ? qw : kw)[lane];
        float v = b2f(*p);
        float mu = wsum64(v) * (1.f / 64.f);
        float ex2 = wsum64(v * v) * (1.f / 64.f);
        float rs = rsqrtf(ex2 - mu * mu + 1e-5f);
        *p = f2b((v - mu) * rs * wt);
    }
}

// ---------------- axial attention: block = (b, line j, head he).
// phase 0: attention within row j (tokens (b,j,*)); phase 1: within column j
// (tokens (b,*,j)). Both use query position i; outputs summed and written to
// A2[token(b,i,j)][he*64 + c]  (the A operand of the final GEMM).
__global__ __launch_bounds__(256) void axial_attn(const u16* __restrict__ qkv,
                                                  u16* __restrict__ A2) {
    __shared__ float Qs[64][68];
    __shared__ float Ks[64][68];
    __shared__ float Vs[64][68];
    float(*Ss)[68] = Qs;   // S overlays Q (guarded by barriers)

    const int bx = blockIdx.x;
    const int he = bx % 12;
    const int j = (bx / 12) & 63;
    const int b = bx / (12 * 64);
    const int tid = threadIdx.x;
    const int p = tid >> 2;    // 0..63 : row (query/token index)
    const int seg = tid & 3;
    const int cb = seg * 16;

    float o[16];
#pragma unroll
    for (int i = 0; i < 16; ++i) o[i] = 0.f;

    for (int phase = 0; phase < 2; ++phase) {
        const size_t tok = (phase == 0) ? ((size_t)((b * 64 + j) * 64 + p))
                                        : ((size_t)((b * 64 + p) * 64 + j));
        const u16* src = qkv + tok * 2304 + he * 64 + cb;
        u16x8 q0 = *(const u16x8*)(src);
        u16x8 q1 = *(const u16x8*)(src + 8);
        u16x8 k0 = *(const u16x8*)(src + 768);
        u16x8 k1 = *(const u16x8*)(src + 776);
        u16x8 v0 = *(const u16x8*)(src + 1536);
        u16x8 v1 = *(const u16x8*)(src + 1544);
#pragma unroll
        for (int i = 0; i < 8; ++i) {
            Qs[p][cb + i] = b2f(q0[i]); Qs[p][cb + 8 + i] = b2f(q1[i]);
            Ks[p][cb + i] = b2f(k0[i]); Ks[p][cb + 8 + i] = b2f(k1[i]);
            Vs[p][cb + i] = b2f(v0[i]); Vs[p][cb + 8 + i] = b2f(v1[i]);
        }
        __syncthreads();

        // S[p][cb..cb+16) = (Q[p] . K[w]) * 1/8
        float d[16];
#pragma unroll
        for (int i = 0; i < 16; ++i) d[i] = 0.f;
        for (int k4 = 0; k4 < 64; k4 += 4) {
            const f4 qv = *(const f4*)&Qs[p][k4];
#pragma unroll
            for (int w2 = 0; w2 < 16; ++w2) {
                const f4 kv = *(const f4*)&Ks[cb + w2][k4];
                d[w2] += qv[0] * kv[0] + qv[1] * kv[1] + qv[2] * kv[2] + qv[3] * kv[3];
            }
        }
        // softmax across the 4 threads (lanes differing in bits 0-1) owning row p
        float mx = -1e30f;
#pragma unroll
        for (int i = 0; i < 16; ++i) { d[i] *= 0.125f; mx = fmaxf(mx, d[i]); }
        mx = fmaxf(mx, __shfl_xor(mx, 1, 64));
        mx = fmaxf(mx, __shfl_xor(mx, 2, 64));
        float sm = 0.f;
#pragma unroll
        for (int i = 0; i < 16; ++i) { d[i] = __expf(d[i] - mx); sm += d[i]; }
        sm += __shfl_xor(sm, 1, 64);
        sm += __shfl_xor(sm, 2, 64);
        const float inv = 1.f / sm;
        __syncthreads();   // all Qs reads done before overwriting with S
#pragma unroll
        for (int i = 0; i < 16; ++i) Ss[p][cb + i] = d[i] * inv;
        __syncthreads();

        // o[p][cb..cb+16) += sum_w S[p][w] * V[w][cb..]
        for (int w4 = 0; w4 < 64; w4 += 4) {
            const f4 pw = *(const f4*)&Ss[p][w4];
#pragma unroll
            for (int dw = 0; dw < 4; ++dw) {
                const float pp = pw[dw];
                const int wr = w4 + dw;
                const f4 va = *(const f4*)&Vs[wr][cb];
                const f4 vb = *(const f4*)&Vs[wr][cb + 4];
                const f4 vc = *(const f4*)&Vs[wr][cb + 8];
                const f4 vd = *(const f4*)&Vs[wr][cb + 12];
#pragma unroll
                for (int q = 0; q < 4; ++q) {
                    o[q] += pp * va[q]; o[4 + q] += pp * vb[q];
                    o[8 + q] += pp * vc[q]; o[12 + q] += pp * vd[q];
                }
            }
        }
        __syncthreads();   // protect tiles before next phase load
    }

    u16* dst = A2 + ((size_t)((b * 64 + p) * 64 + j)) * KFF + he * 64 + cb;
    u16x8 w0, w1;
#pragma unroll
    for (int i = 0; i < 8; ++i) { w0[i] = f2b(o[i]); w1[i] = f2b(o[8 + i]); }
    *(u16x8*)(dst) = w0;
    *(u16x8*)(dst + 8) = w1;
}

extern "C" void kernel_launch(void* const* d_in, const int* in_sizes, int n_in,
                              void* d_out, int out_size, void* d_ws, size_t ws_size,
                              hipStream_t stream) {
    const float* x = (const float*)d_in[0];
    const float* normw = (const float*)d_in[1];
    const float* Wqkv = (const float*)d_in[2];
    const float* bqkv = (const float*)d_in[3];
    const float* qnw = (const float*)d_in[4];
    const float* knw = (const float*)d_in[5];
    const float* Wout = (const float*)d_in[6];
    const float* bout = (const float*)d_in[7];
    const float* Wmlp = (const float*)d_in[8];
    const float* bmlp = (const float*)d_in[9];
    const float* gamma = (const float*)d_in[10];
    float* out = (float*)d_out;

    char* ws = (char*)d_ws;
    u16* xn = (u16*)ws;    ws += (size_t)NTOK * CDIM * 2;
    u16* WqkvT = (u16*)ws; ws += (size_t)NPROJ * CDIM * 2;
    u16* BT2 = (u16*)ws;   ws += (size_t)CDIM * KFF * 2;
    u16* qkv = (u16*)ws;   ws += (size_t)NTOK * 2304 * 2;
    u16* A2 = (u16*)ws;    ws += (size_t)NTOK * KFF * 2;

    // weights -> B^T bf16
    transpose_cast<<<dim3(NPROJ / 32, CDIM / 32), dim3(32, 8), 0, stream>>>(Wqkv, WqkvT, CDIM, NPROJ, CDIM, 0);
    transpose_cast<<<dim3(CDIM / 32, CDIM / 32), dim3(32, 8), 0, stream>>>(Wout, BT2, CDIM, CDIM, KFF, 0);
    transpose_cast<<<dim3(CDIM / 32, 3072 / 32), dim3(32, 8), 0, stream>>>(Wmlp, BT2, 3072, CDIM, KFF, 768);
    // LN(x) -> bf16
    ln_rows<<<NTOK / 4, 256, 0, stream>>>(x, normw, xn);
    // proj GEMM: q,k,v -> qkv buffer; gelu(ff) -> A2[:, 768:3840]
    gemm_bt<0><<<dim3(NPROJ / 128, NTOK / 128), 256, 0, stream>>>(
        xn, WqkvT, NTOK, NPROJ, CDIM, bqkv, nullptr, nullptr, nullptr, qkv, A2, nullptr);
    // per-head LN of q,k in place
    qk_ln<<<NTOK, 256, 0, stream>>>(qkv, qnw, knw);
    // both axial attentions -> A2[:, 0:768]
    axial_attn<<<3072, 256, 0, stream>>>(qkv, A2);
    // final fused GEMM: out = x + gamma * (A2 @ [WoutT|WmlpT] + bout + bmlp)
    gemm_bt<1><<<dim3(CDIM / 128, NTOK / 128), 256, 0, stream>>>(
        A2, BT2, NTOK, CDIM, KFF, bout, bmlp, x, gamma, nullptr, nullptr, out);
}

// Round 5
// 612.090 us; speedup vs baseline: 1.4235x; 1.4235x over previous
//
#include <hip/hip_runtime.h>

typedef unsigned short u16;
typedef unsigned int u32;
typedef short bf16x8 __attribute__((ext_vector_type(8)));
typedef float f4 __attribute__((ext_vector_type(4)));
typedef u16 u16x4 __attribute__((ext_vector_type(4)));
typedef u16 u16x8 __attribute__((ext_vector_type(8)));

#define CDIM 768
#define NPROJ 5376
#define KFF 3840   // combined K for final gemm: 768 (attn) + 3072 (mlp)
#define NTOK 16384

__device__ __forceinline__ u16 f2b(float f) {
    u32 u = __float_as_uint(f);
    u = (u + 0x7fffu + ((u >> 16) & 1u)) >> 16;   // RNE
    return (u16)u;
}
__device__ __forceinline__ float b2f(u16 h) {
    return __uint_as_float(((u32)h) << 16);
}
__device__ __forceinline__ float wsum64(float v) {
#pragma unroll
    for (int m = 32; m > 0; m >>= 1) v += __shfl_xor(v, m, 64);
    return v;
}
__device__ __forceinline__ void gl_lds16(const u16* g, u16* l) {
    __builtin_amdgcn_global_load_lds((__attribute__((address_space(1))) u32*)g,
                                     (__attribute__((address_space(3))) u32*)l,
                                     16, 0, 0);
}

// ---------------- transpose + fp32->bf16 cast: dst[c*dstride+doff+r] = src[r*Cc+c]
__global__ __launch_bounds__(256) void transpose_cast(const float* __restrict__ src,
                                                      u16* __restrict__ dst,
                                                      int R, int Cc, int dstride, int doff) {
    __shared__ float t[32][33];
    int c0 = blockIdx.x * 32, r0 = blockIdx.y * 32;
    int tx = threadIdx.x, ty = threadIdx.y;
#pragma unroll
    for (int i = 0; i < 32; i += 8) {
        int r = r0 + ty + i, c = c0 + tx;
        if (r < R && c < Cc) t[ty + i][tx] = src[(size_t)r * Cc + c];
    }
    __syncthreads();
#pragma unroll
    for (int i = 0; i < 32; i += 8) {
        int c = c0 + ty + i, r = r0 + tx;
        if (r < R && c < Cc) dst[(size_t)c * dstride + doff + r] = f2b(t[tx][ty + i]);
    }
}

// ---------------- LayerNorm over C=768, write bf16. 4 rows/block, one wave per row.
__global__ __launch_bounds__(256) void ln_rows(const float* __restrict__ x,
                                               const float* __restrict__ w,
                                               u16* __restrict__ xn) {
    int row = blockIdx.x * 4 + (threadIdx.x >> 6);
    int lane = threadIdx.x & 63;
    const f4* xr = (const f4*)(x + (size_t)row * CDIM);
    const f4* wr = (const f4*)w;
    f4 v[3];
    float s = 0.f, s2 = 0.f;
#pragma unroll
    for (int i = 0; i < 3; ++i) {
        v[i] = xr[lane + 64 * i];
#pragma unroll
        for (int j = 0; j < 4; ++j) { s += v[i][j]; s2 += v[i][j] * v[i][j]; }
    }
    s = wsum64(s); s2 = wsum64(s2);
    float mu = s * (1.f / 768.f);
    float var = s2 * (1.f / 768.f) - mu * mu;
    float rs = rsqrtf(var + 1e-5f);
    u16x4* xo = (u16x4*)(xn + (size_t)row * CDIM);
#pragma unroll
    for (int i = 0; i < 3; ++i) {
        f4 wv = wr[lane + 64 * i];
        u16x4 pk;
#pragma unroll
        for (int j = 0; j < 4; ++j) pk[j] = f2b((v[i][j] - mu) * rs * wv[j]);
        xo[lane + 64 * i] = pk;
    }
}

// ---------------- bf16 MFMA GEMM, A (M x K) row-major, B^T (N x K) row-major.
// 128x128 block tile, BK=64, XOR-swizzled LDS chunks (conflict-free frag reads),
// 4 waves (2x2), 2x (4x4) 16x16x32 MFMA per staging barrier.
// MODE 0: proj epilogue (+bqkv; cols<2304 -> qkv buf; else fast-gelu -> A2 ff region)
// MODE 1: final epilogue (+bout+bmlp, out = x + gamma*acc)
template <int MODE>
__global__ __launch_bounds__(256) void gemm_bt(
    const u16* __restrict__ A, const u16* __restrict__ B, int M, int N, int K,
    const float* __restrict__ bias0, const float* __restrict__ bias1,
    const float* __restrict__ xres, const float* __restrict__ gamma,
    u16* __restrict__ oqkv, u16* __restrict__ off, float* __restrict__ ofin) {
    __shared__ __align__(16) u16 As[128 * 64];
    __shared__ __align__(16) u16 Bs[128 * 64];
    const int tid = threadIdx.x;
    const int wid = tid >> 6, lane = tid & 63;
    const int wm = wid >> 1, wn = wid & 1;
    const int quad = lane >> 4, l16 = lane & 15;
    const int m0 = blockIdx.y * 128, n0 = blockIdx.x * 128;

    f4 acc[4][4] = {};

    // staging: each glds16 call moves 8 rows x 128B; 4 calls/wave for A, 4 for B.
    const int rl = lane >> 3;                   // row within call: 0..7
    const int csw = ((lane & 7) ^ rl) * 8;      // XOR-swizzled source chunk (u16 units)
    const u16* aptr[4]; const u16* bptr[4];
    u16* alds[4]; u16* blds[4];
#pragma unroll
    for (int jj = 0; jj < 4; ++jj) {
        const int r0 = wid * 32 + jj * 8;
        aptr[jj] = A + (size_t)(m0 + r0 + rl) * K + csw;
        bptr[jj] = B + (size_t)(n0 + r0 + rl) * K + csw;
        alds[jj] = As + r0 * 64;
        blds[jj] = Bs + r0 * 64;
    }
    const int swl = (l16 & 7) * 8;              // read-side row-swizzle term (u16)

    for (int kt = 0; kt < K; kt += 64) {
#pragma unroll
        for (int jj = 0; jj < 4; ++jj) {
            gl_lds16(aptr[jj] + kt, alds[jj]);
            gl_lds16(bptr[jj] + kt, blds[jj]);
        }
        __syncthreads();
#pragma unroll
        for (int kt2 = 0; kt2 < 2; ++kt2) {
            const int chunk = (kt2 * 4 + quad) * 8;      // logical k-chunk (u16)
            bf16x8 af[4], bfv[4];
#pragma unroll
            for (int mi = 0; mi < 4; ++mi)
                af[mi] = *(const bf16x8*)(As + (wm * 64 + mi * 16 + l16) * 64 + (chunk ^ swl));
#pragma unroll
            for (int ni = 0; ni < 4; ++ni)
                bfv[ni] = *(const bf16x8*)(Bs + (wn * 64 + ni * 16 + l16) * 64 + (chunk ^ swl));
#pragma unroll
            for (int mi = 0; mi < 4; ++mi)
#pragma unroll
                for (int ni = 0; ni < 4; ++ni)
                    acc[mi][ni] = __builtin_amdgcn_mfma_f32_16x16x32_bf16(af[mi], bfv[ni], acc[mi][ni], 0, 0, 0);
        }
        __syncthreads();
    }

#pragma unroll
    for (int mi = 0; mi < 4; ++mi) {
#pragma unroll
        for (int ni = 0; ni < 4; ++ni) {
            const int col = n0 + wn * 64 + ni * 16 + l16;
            const int rowb = m0 + wm * 64 + mi * 16 + quad * 4;
            if (MODE == 0) {
                const float bc = bias0[col];
#pragma unroll
                for (int r = 0; r < 4; ++r) {
                    float vv = acc[mi][ni][r] + bc;
                    const int m = rowb + r;
                    if (col < 2304) {
                        oqkv[(size_t)m * 2304 + col] = f2b(vv);
                    } else {
                        // fast gelu: x*sigmoid(1.5957691216x + 0.0713548162x^3)
                        float u2 = vv * (-1.5957691216f) - 0.0713548162f * vv * vv * vv;
                        float g = vv / (1.f + __expf(u2));
                        off[(size_t)m * KFF + 768 + (col - 2304)] = f2b(g);
                    }
                }
            } else {
                const float bc = bias0[col] + bias1[col];
                const float gm = gamma[col];
#pragma unroll
                for (int r = 0; r < 4; ++r) {
                    const int m = rowb + r;
                    float vv = acc[mi][ni][r] + bc;
                    ofin[(size_t)m * CDIM + col] = xres[(size_t)m * CDIM + col] + gm * vv;
                }
            }
        }
    }
}

// ---------------- per-head LN of q and k (64-elem rows), in place on bf16 qkv buffer.
__global__ __launch_bounds__(256) void qk_ln(u16* __restrict__ qkv,
                                             const float* __restrict__ qw,
                                             const float* __restrict__ kw) {
    const size_t m = blockIdx.x;
    const int w = threadIdx.x >> 6, lane = threadIdx.x & 63;
#pragma unroll
    for (int it = 0; it < 6; ++it) {
        const int h = w + 4 * it;   // 0..23
        const int isq = (h < 12);
        const int he = isq ? h : h - 12;
        u16* p = qkv + m * 2304 + (isq ? 0 : 768) + he * 64 + lane;
        const float wt = (isq ? qw : kw)[lane];
        float v = b2f(*p);
        float mu = wsum64(v) * (1.f / 64.f);
        float ex2 = wsum64(v * v) * (1.f / 64.f);
        float rs = rsqrtf(ex2 - mu * mu + 1e-5f);
        *p = f2b((v - mu) * rs * wt);
    }
}

// ---------------- MFMA axial attention: block = (b, line j, head he), 4 waves.
// phase 0 = attention within row j; phase 1 = within column j; outputs (same
// query position i) accumulate in registers, one write to A2[tok(b,i,j)].
// S^T = K.Q^T via mfma(K-rows, Q-rows)  (k-dim lands on the C-layout ROW axis,
// so softmax is per-lane over 16 regs + 2 quad shuffles). P transposed into
// LDS (b64 writes), O = P.V via mfma(P-rows, V^T-rows) with V^T built at load.
// All LDS tiles use 8-chunk XOR swizzle -> conflict-free b128 frag reads.
// Staging uses plain vector loads + ds_write (no async DMA in this kernel).
__global__ __launch_bounds__(256) void axial_attn_mfma(const u16* __restrict__ qkv,
                                                       u16* __restrict__ A2) {
    __shared__ __align__(16) u16 Qs[64 * 64];
    __shared__ __align__(16) u16 Ks[64 * 64];
    __shared__ __align__(16) u16 Vt[64 * 64];   // V^T[c][k]
    __shared__ __align__(16) u16 Ps[64 * 64];   // P[q][k]

    const int bx = blockIdx.x;
    const int he = bx % 12;
    const int j = (bx / 12) & 63;
    const int b = bx / (12 * 64);
    const int tid = threadIdx.x;
    const int w = tid >> 6, lane = tid & 63;
    const int l16 = lane & 15, quad = lane >> 4;
    const int qb = w * 16;
    const int swl = (l16 & 7) * 8;          // read-side swizzle term (u16 units)

    f4 acc_o[4] = {};

    // staging thread mapping: row r = tid>>2 (0..63), 16-col segment c0 = (tid&3)*16
    const int sr = tid >> 2;
    const int sc = (tid & 3) * 16;
    const int ch0 = sc >> 3;                // first logical 8-chunk of this segment

    for (int phase = 0; phase < 2; ++phase) {
        const size_t tok = (phase == 0) ? (size_t)((b * 64 + j) * 64 + sr)
                                        : (size_t)((b * 64 + sr) * 64 + j);
        const u16* src = qkv + tok * 2304 + he * 64 + sc;
        // Q, K rows: swizzled b128 stores (phys chunk = logical ^ (row&7))
        {
            u16x8 q0 = *(const u16x8*)(src);
            u16x8 q1 = *(const u16x8*)(src + 8);
            u16x8 k0 = *(const u16x8*)(src + 768);
            u16x8 k1 = *(const u16x8*)(src + 776);
            const int p0 = (ch0 ^ (sr & 7)) * 8;
            const int p1 = ((ch0 + 1) ^ (sr & 7)) * 8;
            *(u16x8*)(Qs + sr * 64 + p0) = q0;
            *(u16x8*)(Qs + sr * 64 + p1) = q1;
            *(u16x8*)(Ks + sr * 64 + p0) = k0;
            *(u16x8*)(Ks + sr * 64 + p1) = k1;
        }
        // V transposed: thread owns (k = sr, c in [sc, sc+16))
        {
            u16x8 v0 = *(const u16x8*)(src + 1536);
            u16x8 v1 = *(const u16x8*)(src + 1544);
#pragma unroll
            for (int i = 0; i < 16; ++i) {
                const int c = sc + i;
                const u16 val = (i < 8) ? v0[i] : v1[i - 8];
                Vt[c * 64 + ((((sr >> 3) ^ (c & 7)) << 3) | (sr & 7))] = val;
            }
        }
        __syncthreads();

        // ---- S^T tiles: D[m=k-idx][n=q], this wave's q-cols = qb..qb+15
        f4 st[4] = {};
#pragma unroll
        for (int kt = 0; kt < 2; ++kt) {
            const int chunk = (kt * 4 + quad) * 8;
            const bf16x8 bq = *(const bf16x8*)(Qs + (qb + l16) * 64 + (chunk ^ swl));
#pragma unroll
            for (int mt = 0; mt < 4; ++mt) {
                const bf16x8 ak = *(const bf16x8*)(Ks + (mt * 16 + l16) * 64 + (chunk ^ swl));
                st[mt] = __builtin_amdgcn_mfma_f32_16x16x32_bf16(ak, bq, st[mt], 0, 0, 0);
            }
        }

        // ---- softmax over k (= m axis): per-lane 16 values + cross-quad shuffles
        float sv[16];
        float mx = -1e30f;
#pragma unroll
        for (int mt = 0; mt < 4; ++mt)
#pragma unroll
            for (int r = 0; r < 4; ++r) {
                const float s = st[mt][r] * 0.125f;
                sv[mt * 4 + r] = s;
                mx = fmaxf(mx, s);
            }
        mx = fmaxf(mx, __shfl_xor(mx, 16, 64));
        mx = fmaxf(mx, __shfl_xor(mx, 32, 64));
        float sm = 0.f;
#pragma unroll
        for (int i = 0; i < 16; ++i) { sv[i] = __expf(sv[i] - mx); sm += sv[i]; }
        sm += __shfl_xor(sm, 16, 64);
        sm += __shfl_xor(sm, 32, 64);
        const float inv = 1.f / sm;

        // ---- write P[q][k] (transpose out of C-layout), swizzled, b64 stores
#pragma unroll
        for (int mt = 0; mt < 4; ++mt) {
            u16x4 pk;
#pragma unroll
            for (int r = 0; r < 4; ++r) pk[r] = f2b(sv[mt * 4 + r] * inv);
            const int kbase = mt * 16 + quad * 4;
            const int phys = (kbase >> 3) ^ (l16 & 7);
            *(u16x4*)(Ps + (qb + l16) * 64 + (phys << 3) + (kbase & 7)) = pk;
        }
        __syncthreads();

        // ---- O += P.V : m-tile = this wave's q rows, n-tiles over c
#pragma unroll
        for (int kt = 0; kt < 2; ++kt) {
            const int chunk = (kt * 4 + quad) * 8;
            const bf16x8 ap = *(const bf16x8*)(Ps + (qb + l16) * 64 + (chunk ^ swl));
#pragma unroll
            for (int nt = 0; nt < 4; ++nt) {
                const bf16x8 bv = *(const bf16x8*)(Vt + (nt * 16 + l16) * 64 + (chunk ^ swl));
                acc_o[nt] = __builtin_amdgcn_mfma_f32_16x16x32_bf16(ap, bv, acc_o[nt], 0, 0, 0);
            }
        }
        __syncthreads();   // protect tiles before next phase reload
    }

    // ---- store: q = qb + quad*4 + r, c = nt*16 + l16
#pragma unroll
    for (int nt = 0; nt < 4; ++nt)
#pragma unroll
        for (int r = 0; r < 4; ++r) {
            const int q = qb + quad * 4 + r;
            const int c = nt * 16 + l16;
            A2[((size_t)((b * 64 + q) * 64 + j)) * KFF + he * 64 + c] = f2b(acc_o[nt][r]);
        }
}

extern "C" void kernel_launch(void* const* d_in, const int* in_sizes, int n_in,
                              void* d_out, int out_size, void* d_ws, size_t ws_size,
                              hipStream_t stream) {
    const float* x = (const float*)d_in[0];
    const float* normw = (const float*)d_in[1];
    const float* Wqkv = (const float*)d_in[2];
    const float* bqkv = (const float*)d_in[3];
    const float* qnw = (const float*)d_in[4];
    const float* knw = (const float*)d_in[5];
    const float* Wout = (const float*)d_in[6];
    const float* bout = (const float*)d_in[7];
    const float* Wmlp = (const float*)d_in[8];
    const float* bmlp = (const float*)d_in[9];
    const float* gamma = (const float*)d_in[10];
    float* out = (float*)d_out;

    char* ws = (char*)d_ws;
    u16* xn = (u16*)ws;    ws += (size_t)NTOK * CDIM * 2;
    u16* WqkvT = (u16*)ws; ws += (size_t)NPROJ * CDIM * 2;
    u16* BT2 = (u16*)ws;   ws += (size_t)CDIM * KFF * 2;
    u16* qkv = (u16*)ws;   ws += (size_t)NTOK * 2304 * 2;
    u16* A2 = (u16*)ws;    ws += (size_t)NTOK * KFF * 2;

    // weights -> B^T bf16
    transpose_cast<<<dim3(NPROJ / 32, CDIM / 32), dim3(32, 8), 0, stream>>>(Wqkv, WqkvT, CDIM, NPROJ, CDIM, 0);
    transpose_cast<<<dim3(CDIM / 32, CDIM / 32), dim3(32, 8), 0, stream>>>(Wout, BT2, CDIM, CDIM, KFF, 0);
    transpose_cast<<<dim3(CDIM / 32, 3072 / 32), dim3(32, 8), 0, stream>>>(Wmlp, BT2, 3072, CDIM, KFF, 768);
    // LN(x) -> bf16
    ln_rows<<<NTOK / 4, 256, 0, stream>>>(x, normw, xn);
    // proj GEMM: q,k,v -> qkv buffer; gelu(ff) -> A2[:, 768:3840]
    gemm_bt<0><<<dim3(NPROJ / 128, NTOK / 128), 256, 0, stream>>>(
        xn, WqkvT, NTOK, NPROJ, CDIM, bqkv, nullptr, nullptr, nullptr, qkv, A2, nullptr);
    // per-head LN of q,k in place
    qk_ln<<<NTOK, 256, 0, stream>>>(qkv, qnw, knw);
    // both axial attentions -> A2[:, 0:768]
    axial_attn_mfma<<<3072, 256, 0, stream>>>(qkv, A2);
    // final fused GEMM: out = x + gamma * (A2 @ [WoutT|WmlpT] + bout + bmlp)
    gemm_bt<1><<<dim3(CDIM / 128, NTOK / 128), 256, 0, stream>>>(
        A2, BT2, NTOK, CDIM, KFF, bout, bmlp, x, gamma, nullptr, nullptr, out);
}

// Round 6
// 496.472 us; speedup vs baseline: 1.7550x; 1.2329x over previous
//
#include <hip/hip_runtime.h>

typedef unsigned short u16;
typedef unsigned int u32;
typedef unsigned char u8;
typedef long i64;
typedef float f4 __attribute__((ext_vector_type(4)));

#define CDIM 768
#define NPROJ 5376
#define KFF 3840   // combined K for final gemm: 768 (attn) + 3072 (mlp)
#define NTOK 16384

// ---------------- fp8 e4m3 (OCP) conversion helpers, HW cvt when available
__device__ __forceinline__ u8 f2fp8(float f) {
#if __has_builtin(__builtin_amdgcn_cvt_pk_fp8_f32)
    return (u8)(__builtin_amdgcn_cvt_pk_fp8_f32(f, f, 0, false) & 0xff);
#else
    u32 u = __float_as_uint(f);
    u32 s = (u >> 24) & 0x80u;
    float a = fabsf(f);
    a = fminf(a, 448.f);
    if (a < 0.015625f) return (u8)(s | (u32)(a * 512.f + 0.5f));
    u32 b = __float_as_uint(a);
    b += 0x0007FFFFu + ((b >> 20) & 1u);
    u32 e = b >> 23, m = (b >> 20) & 7u;
    u32 code = ((e - 120u) << 3) | m;
    if (code > 0x7Eu) code = 0x7Eu;
    return (u8)(s | code);
#endif
}
__device__ __forceinline__ u32 pk4_fp8(float a, float b, float c, float d) {
#if __has_builtin(__builtin_amdgcn_cvt_pk_fp8_f32)
    u32 lo = (u32)__builtin_amdgcn_cvt_pk_fp8_f32(a, b, 0, false);
    return (u32)__builtin_amdgcn_cvt_pk_fp8_f32(c, d, lo, true);
#else
    return (u32)f2fp8(a) | ((u32)f2fp8(b) << 8) | ((u32)f2fp8(c) << 16) | ((u32)f2fp8(d) << 24);
#endif
}
__device__ __forceinline__ float fp8_to_f32(u32 v) {
#if __has_builtin(__builtin_amdgcn_cvt_f32_fp8)
    return __builtin_amdgcn_cvt_f32_fp8((int)v, 0);
#else
    u32 s = v >> 7, e = (v >> 3) & 15u, m = v & 7u;
    float mag = e ? __uint_as_float(((e + 120u) << 23) | (m << 20))
                  : (float)m * 0.001953125f;
    return s ? -mag : mag;
#endif
}

__device__ __forceinline__ float wsum64(float v) {
#pragma unroll
    for (int m = 32; m > 0; m >>= 1) v += __shfl_xor(v, m, 64);
    return v;
}
__device__ __forceinline__ void gl_lds16(const u8* g, u8* l) {
    __builtin_amdgcn_global_load_lds((__attribute__((address_space(1))) u32*)g,
                                     (__attribute__((address_space(3))) u32*)l,
                                     16, 0, 0);
}

// ---------------- transpose + fp32->fp8 cast: dst[c*dstride+doff+r] = src[r*Cc+c]
__global__ __launch_bounds__(256) void transpose_cast(const float* __restrict__ src,
                                                      u8* __restrict__ dst,
                                                      int R, int Cc, int dstride, int doff) {
    __shared__ float t[32][33];
    int c0 = blockIdx.x * 32, r0 = blockIdx.y * 32;
    int tx = threadIdx.x, ty = threadIdx.y;
#pragma unroll
    for (int i = 0; i < 32; i += 8) {
        int r = r0 + ty + i, c = c0 + tx;
        if (r < R && c < Cc) t[ty + i][tx] = src[(size_t)r * Cc + c];
    }
    __syncthreads();
#pragma unroll
    for (int i = 0; i < 32; i += 8) {
        int c = c0 + ty + i, r = r0 + tx;
        if (r < R && c < Cc) dst[(size_t)c * dstride + doff + r] = f2fp8(t[tx][ty + i]);
    }
}

// ---------------- LayerNorm over C=768, write fp8. 4 rows/block, one wave per row.
__global__ __launch_bounds__(256) void ln_rows(const float* __restrict__ x,
                                               const float* __restrict__ w,
                                               u8* __restrict__ xn) {
    int row = blockIdx.x * 4 + (threadIdx.x >> 6);
    int lane = threadIdx.x & 63;
    const f4* xr = (const f4*)(x + (size_t)row * CDIM);
    const f4* wr = (const f4*)w;
    f4 v[3];
    float s = 0.f, s2 = 0.f;
#pragma unroll
    for (int i = 0; i < 3; ++i) {
        v[i] = xr[lane + 64 * i];
#pragma unroll
        for (int j = 0; j < 4; ++j) { s += v[i][j]; s2 += v[i][j] * v[i][j]; }
    }
    s = wsum64(s); s2 = wsum64(s2);
    float mu = s * (1.f / 768.f);
    float var = s2 * (1.f / 768.f) - mu * mu;
    float rs = rsqrtf(var + 1e-5f);
    u32* xo = (u32*)(xn + (size_t)row * CDIM);
#pragma unroll
    for (int i = 0; i < 3; ++i) {
        f4 wv = wr[lane + 64 * i];
        xo[lane + 64 * i] = pk4_fp8((v[i][0] - mu) * rs * wv[0], (v[i][1] - mu) * rs * wv[1],
                                    (v[i][2] - mu) * rs * wv[2], (v[i][3] - mu) * rs * wv[3]);
    }
}

// ---------------- fp8 MFMA GEMM, A (M x K) row-major fp8, B^T (N x K) row-major fp8.
// 128x128 block tile, BK=64 (bytes), XOR-swizzled (16B-pair granule) LDS,
// 4 waves (2x2), 2x (4x4) 16x16x32 fp8 MFMA per staging barrier.
// MODE 0: proj epilogue (+bqkv; cols<2304 -> fp8 qkv; else fast-gelu -> fp8 A2 ff)
// MODE 1: final epilogue (+bout+bmlp, out = x + gamma*acc, fp32)
template <int MODE>
__global__ __launch_bounds__(256) void gemm_bt(
    const u8* __restrict__ A, const u8* __restrict__ B, int M, int N, int K,
    const float* __restrict__ bias0, const float* __restrict__ bias1,
    const float* __restrict__ xres, const float* __restrict__ gamma,
    u8* __restrict__ oqkv, u8* __restrict__ off, float* __restrict__ ofin) {
    __shared__ __align__(16) u8 As[128 * 64];
    __shared__ __align__(16) u8 Bs[128 * 64];
    const int tid = threadIdx.x;
    const int wid = tid >> 6, lane = tid & 63;
    const int wm = wid >> 1, wn = wid & 1;
    const int quad = lane >> 4, l16 = lane & 15;
    const int m0 = blockIdx.y * 128, n0 = blockIdx.x * 128;

    f4 acc[4][4] = {};

    // staging: each glds16 call = 16 rows x 64B. 2 A-calls + 2 B-calls per wave.
    // write-side swizzle: phys 16B-chunk (lane&3) holds logical chunk
    // (lane&3) ^ ((row&6)>>1)  -> source chunk = (lane&3) ^ ((lane>>3)&3)
    const int srow = lane >> 2;                       // 0..15 within call
    const int schunk = ((lane & 3) ^ ((lane >> 3) & 3)) * 16;
    const u8* aptr[2]; const u8* bptr[2];
    u8* alds[2]; u8* blds[2];
#pragma unroll
    for (int jj = 0; jj < 2; ++jj) {
        const int r0 = wid * 32 + jj * 16;
        aptr[jj] = A + (size_t)(m0 + r0 + srow) * K + schunk;
        bptr[jj] = B + (size_t)(n0 + r0 + srow) * K + schunk;
        alds[jj] = As + r0 * 64;
        blds[jj] = Bs + r0 * 64;
    }
    const int swl = l16 & 6;                          // read-side swizzle (8B-slot units)

    for (int kt = 0; kt < K; kt += 64) {
#pragma unroll
        for (int jj = 0; jj < 2; ++jj) {
            gl_lds16(aptr[jj] + kt, alds[jj]);
            gl_lds16(bptr[jj] + kt, blds[jj]);
        }
        __syncthreads();
#pragma unroll
        for (int kt2 = 0; kt2 < 2; ++kt2) {
            const int slot = kt2 * 4 + quad;          // logical 8B slot
            const int boff = (slot ^ swl) * 8;        // physical byte offset
            i64 af[4], bfv[4];
#pragma unroll
            for (int mi = 0; mi < 4; ++mi)
                af[mi] = *(const i64*)(As + (wm * 64 + mi * 16 + l16) * 64 + boff);
#pragma unroll
            for (int ni = 0; ni < 4; ++ni)
                bfv[ni] = *(const i64*)(Bs + (wn * 64 + ni * 16 + l16) * 64 + boff);
#pragma unroll
            for (int mi = 0; mi < 4; ++mi)
#pragma unroll
                for (int ni = 0; ni < 4; ++ni)
                    acc[mi][ni] = __builtin_amdgcn_mfma_f32_16x16x32_fp8_fp8(af[mi], bfv[ni], acc[mi][ni], 0, 0, 0);
        }
        __syncthreads();
    }

#pragma unroll
    for (int mi = 0; mi < 4; ++mi) {
#pragma unroll
        for (int ni = 0; ni < 4; ++ni) {
            const int col = n0 + wn * 64 + ni * 16 + l16;
            const int rowb = m0 + wm * 64 + mi * 16 + quad * 4;
            if (MODE == 0) {
                const float bc = bias0[col];
#pragma unroll
                for (int r = 0; r < 4; ++r) {
                    float vv = acc[mi][ni][r] + bc;
                    const int m = rowb + r;
                    if (col < 2304) {
                        oqkv[(size_t)m * 2304 + col] = f2fp8(vv);
                    } else {
                        // fast gelu: x*sigmoid(1.5957691216x + 0.0713548162x^3)
                        float u2 = vv * (-1.5957691216f) - 0.0713548162f * vv * vv * vv;
                        float g = vv / (1.f + __expf(u2));
                        off[(size_t)m * KFF + 768 + (col - 2304)] = f2fp8(g);
                    }
                }
            } else {
                const float bc = bias0[col] + bias1[col];
                const float gm = gamma[col];
#pragma unroll
                for (int r = 0; r < 4; ++r) {
                    const int m = rowb + r;
                    float vv = acc[mi][ni][r] + bc;
                    ofin[(size_t)m * CDIM + col] = xres[(size_t)m * CDIM + col] + gm * vv;
                }
            }
        }
    }
}

// ---------------- per-head LN of q and k (64-elem rows), in place on fp8 qkv buffer.
__global__ __launch_bounds__(256) void qk_ln(u8* __restrict__ qkv,
                                             const float* __restrict__ qw,
                                             const float* __restrict__ kw) {
    const size_t m = blockIdx.x;
    const int w = threadIdx.x >> 6, lane = threadIdx.x & 63;
#pragma unroll
    for (int it = 0; it < 6; ++it) {
        const int h = w + 4 * it;   // 0..23
        const int isq = (h < 12);
        const int he = isq ? h : h - 12;
        u8* p = qkv + m * 2304 + (isq ? 0 : 768) + he * 64 + lane;
        const float wt = (isq ? qw : kw)[lane];
        float v = fp8_to_f32(*p);
        float mu = wsum64(v) * (1.f / 64.f);
        float ex2 = wsum64(v * v) * (1.f / 64.f);
        float rs = rsqrtf(ex2 - mu * mu + 1e-5f);
        *p = f2fp8((v - mu) * rs * wt);
    }
}

// ---------------- fp8 MFMA axial attention: block = (b, line j, head he), 4 waves.
// phase 0 = row-j attention, phase 1 = column-j; register-accumulated, one
// fp8 write to A2[tok(b,i,j)]. S^T = K.Q^T (softmax per-lane + 2 quad
// shuffles), P->LDS (u32 packed), O = P.V with V^T built at load.
// All LDS tiles padded to 72B rows -> conflict-free 8B frag reads, no swizzle.
__global__ __launch_bounds__(256) void axial_attn_mfma(const u8* __restrict__ qkv,
                                                       u8* __restrict__ A2) {
    __shared__ __align__(16) u8 Qs[64 * 72];
    __shared__ __align__(16) u8 Ks[64 * 72];
    __shared__ __align__(16) u8 Vt[64 * 72];   // V^T[c][k]
    __shared__ __align__(16) u8 Ps[64 * 72];   // P[q][k]

    const int bx = blockIdx.x;
    const int he = bx % 12;
    const int j = (bx / 12) & 63;
    const int b = bx / (12 * 64);
    const int tid = threadIdx.x;
    const int w = tid >> 6, lane = tid & 63;
    const int l16 = lane & 15, quad = lane >> 4;
    const int qb = w * 16;

    f4 acc_o[4] = {};

    // staging thread mapping: row sr = tid>>2 (0..63), 16B segment sc = (tid&3)*16
    const int sr = tid >> 2;
    const int sc = (tid & 3) * 16;

    for (int phase = 0; phase < 2; ++phase) {
        const size_t tok = (phase == 0) ? (size_t)((b * 64 + j) * 64 + sr)
                                        : (size_t)((b * 64 + sr) * 64 + j);
        const u8* src = qkv + tok * 2304 + he * 64 + sc;
        {
            uint4 qv = *(const uint4*)(src);
            uint4 kv = *(const uint4*)(src + 768);
            *(uint4*)(Qs + sr * 72 + sc) = qv;
            *(uint4*)(Ks + sr * 72 + sc) = kv;
        }
        // V transposed: thread owns (k = sr, c in [sc, sc+16))
        {
            uint4 vv = *(const uint4*)(src + 1536);
            const u8* vb = (const u8*)&vv;
#pragma unroll
            for (int i = 0; i < 16; ++i) Vt[(sc + i) * 72 + sr] = vb[i];
        }
        __syncthreads();

        // ---- S^T tiles: D[m=k-idx][n=q], this wave's q-cols = qb..qb+15
        f4 st[4] = {};
#pragma unroll
        for (int kt = 0; kt < 2; ++kt) {
            const int boff = (kt * 4 + quad) * 8;
            const i64 bq = *(const i64*)(Qs + (qb + l16) * 72 + boff);
#pragma unroll
            for (int mt = 0; mt < 4; ++mt) {
                const i64 ak = *(const i64*)(Ks + (mt * 16 + l16) * 72 + boff);
                st[mt] = __builtin_amdgcn_mfma_f32_16x16x32_fp8_fp8(ak, bq, st[mt], 0, 0, 0);
            }
        }

        // ---- softmax over k (= m axis): per-lane 16 values + cross-quad shuffles
        float sv[16];
        float mx = -1e30f;
#pragma unroll
        for (int mt = 0; mt < 4; ++mt)
#pragma unroll
            for (int r = 0; r < 4; ++r) {
                const float s = st[mt][r] * 0.125f;
                sv[mt * 4 + r] = s;
                mx = fmaxf(mx, s);
            }
        mx = fmaxf(mx, __shfl_xor(mx, 16, 64));
        mx = fmaxf(mx, __shfl_xor(mx, 32, 64));
        float sm = 0.f;
#pragma unroll
        for (int i = 0; i < 16; ++i) { sv[i] = __expf(sv[i] - mx); sm += sv[i]; }
        sm += __shfl_xor(sm, 16, 64);
        sm += __shfl_xor(sm, 32, 64);
        const float inv = 1.f / sm;

        // ---- write P[q][k] (transpose out of C-layout), packed u32 stores
#pragma unroll
        for (int mt = 0; mt < 4; ++mt) {
            const int kbase = mt * 16 + quad * 4;
            *(u32*)(Ps + (qb + l16) * 72 + kbase) =
                pk4_fp8(sv[mt * 4] * inv, sv[mt * 4 + 1] * inv,
                        sv[mt * 4 + 2] * inv, sv[mt * 4 + 3] * inv);
        }
        __syncthreads();

        // ---- O += P.V : m-tile = this wave's q rows, n-tiles over c
#pragma unroll
        for (int kt = 0; kt < 2; ++kt) {
            const int boff = (kt * 4 + quad) * 8;
            const i64 ap = *(const i64*)(Ps + (qb + l16) * 72 + boff);
#pragma unroll
            for (int nt = 0; nt < 4; ++nt) {
                const i64 bv = *(const i64*)(Vt + (nt * 16 + l16) * 72 + boff);
                acc_o[nt] = __builtin_amdgcn_mfma_f32_16x16x32_fp8_fp8(ap, bv, acc_o[nt], 0, 0, 0);
            }
        }
        __syncthreads();   // protect tiles before next phase reload
    }

    // ---- store: q = qb + quad*4 + r, c = nt*16 + l16
#pragma unroll
    for (int nt = 0; nt < 4; ++nt)
#pragma unroll
        for (int r = 0; r < 4; ++r) {
            const int q = qb + quad * 4 + r;
            const int c = nt * 16 + l16;
            A2[((size_t)((b * 64 + q) * 64 + j)) * KFF + he * 64 + c] = f2fp8(acc_o[nt][r]);
        }
}

extern "C" void kernel_launch(void* const* d_in, const int* in_sizes, int n_in,
                              void* d_out, int out_size, void* d_ws, size_t ws_size,
                              hipStream_t stream) {
    const float* x = (const float*)d_in[0];
    const float* normw = (const float*)d_in[1];
    const float* Wqkv = (const float*)d_in[2];
    const float* bqkv = (const float*)d_in[3];
    const float* qnw = (const float*)d_in[4];
    const float* knw = (const float*)d_in[5];
    const float* Wout = (const float*)d_in[6];
    const float* bout = (const float*)d_in[7];
    const float* Wmlp = (const float*)d_in[8];
    const float* bmlp = (const float*)d_in[9];
    const float* gamma = (const float*)d_in[10];
    float* out = (float*)d_out;

    char* ws = (char*)d_ws;
    u8* xn = (u8*)ws;    ws += (size_t)NTOK * CDIM;
    u8* WqkvT = (u8*)ws; ws += (size_t)NPROJ * CDIM;
    u8* BT2 = (u8*)ws;   ws += (size_t)CDIM * KFF;
    u8* qkv = (u8*)ws;   ws += (size_t)NTOK * 2304;
    u8* A2 = (u8*)ws;    ws += (size_t)NTOK * KFF;

    // weights -> B^T fp8
    transpose_cast<<<dim3(NPROJ / 32, CDIM / 32), dim3(32, 8), 0, stream>>>(Wqkv, WqkvT, CDIM, NPROJ, CDIM, 0);
    transpose_cast<<<dim3(CDIM / 32, CDIM / 32), dim3(32, 8), 0, stream>>>(Wout, BT2, CDIM, CDIM, KFF, 0);
    transpose_cast<<<dim3(CDIM / 32, 3072 / 32), dim3(32, 8), 0, stream>>>(Wmlp, BT2, 3072, CDIM, KFF, 768);
    // LN(x) -> fp8
    ln_rows<<<NTOK / 4, 256, 0, stream>>>(x, normw, xn);
    // proj GEMM: q,k,v -> qkv buffer; gelu(ff) -> A2[:, 768:3840]
    gemm_bt<0><<<dim3(NPROJ / 128, NTOK / 128), 256, 0, stream>>>(
        xn, WqkvT, NTOK, NPROJ, CDIM, bqkv, nullptr, nullptr, nullptr, qkv, A2, nullptr);
    // per-head LN of q,k in place
    qk_ln<<<NTOK, 256, 0, stream>>>(qkv, qnw, knw);
    // both axial attentions -> A2[:, 0:768]
    axial_attn_mfma<<<3072, 256, 0, stream>>>(qkv, A2);
    // final fused GEMM: out = x + gamma * (A2 @ [WoutT|WmlpT] + bout + bmlp)
    gemm_bt<1><<<dim3(CDIM / 128, NTOK / 128), 256, 0, stream>>>(
        A2, BT2, NTOK, CDIM, KFF, bout, bmlp, x, gamma, nullptr, nullptr, out);
}

// Round 7
// 421.376 us; speedup vs baseline: 2.0678x; 1.1782x over previous
//
#include <hip/hip_runtime.h>

typedef unsigned short u16;
typedef unsigned int u32;
typedef unsigned char u8;
typedef long i64;
typedef float f4 __attribute__((ext_vector_type(4)));
typedef int i32x8 __attribute__((ext_vector_type(8)));

#define CDIM 768
#define NPROJ 5376
#define KFF 3840   // combined K for final gemm: 768 (attn) + 3072 (mlp)
#define NTOK 16384

// ---------------- fp8 e4m3 (OCP) conversion helpers, HW cvt when available
__device__ __forceinline__ u8 f2fp8(float f) {
#if __has_builtin(__builtin_amdgcn_cvt_pk_fp8_f32)
    return (u8)(__builtin_amdgcn_cvt_pk_fp8_f32(f, f, 0, false) & 0xff);
#else
    u32 u = __float_as_uint(f);
    u32 s = (u >> 24) & 0x80u;
    float a = fabsf(f);
    a = fminf(a, 448.f);
    if (a < 0.015625f) return (u8)(s | (u32)(a * 512.f + 0.5f));
    u32 b = __float_as_uint(a);
    b += 0x0007FFFFu + ((b >> 20) & 1u);
    u32 e = b >> 23, m = (b >> 20) & 7u;
    u32 code = ((e - 120u) << 3) | m;
    if (code > 0x7Eu) code = 0x7Eu;
    return (u8)(s | code);
#endif
}
__device__ __forceinline__ u32 pk4_fp8(float a, float b, float c, float d) {
#if __has_builtin(__builtin_amdgcn_cvt_pk_fp8_f32)
    u32 lo = (u32)__builtin_amdgcn_cvt_pk_fp8_f32(a, b, 0, false);
    return (u32)__builtin_amdgcn_cvt_pk_fp8_f32(c, d, lo, true);
#else
    return (u32)f2fp8(a) | ((u32)f2fp8(b) << 8) | ((u32)f2fp8(c) << 16) | ((u32)f2fp8(d) << 24);
#endif
}
__device__ __forceinline__ float fp8_to_f32(u32 v) {
#if __has_builtin(__builtin_amdgcn_cvt_f32_fp8)
    return __builtin_amdgcn_cvt_f32_fp8((int)v, 0);
#else
    u32 s = v >> 7, e = (v >> 3) & 15u, m = v & 7u;
    float mag = e ? __uint_as_float(((e + 120u) << 23) | (m << 20))
                  : (float)m * 0.001953125f;
    return s ? -mag : mag;
#endif
}

__device__ __forceinline__ float wsum64(float v) {
#pragma unroll
    for (int m = 32; m > 0; m >>= 1) v += __shfl_xor(v, m, 64);
    return v;
}
__device__ __forceinline__ void gl_lds16(const u8* g, u8* l) {
    __builtin_amdgcn_global_load_lds((__attribute__((address_space(1))) u32*)g,
                                     (__attribute__((address_space(3))) u32*)l,
                                     16, 0, 0);
}

// ---------------- transpose + fp32->fp8 cast: dst[c*dstride+doff+r] = src[r*Cc+c]
__global__ __launch_bounds__(256) void transpose_cast(const float* __restrict__ src,
                                                      u8* __restrict__ dst,
                                                      int R, int Cc, int dstride, int doff) {
    __shared__ float t[32][33];
    int c0 = blockIdx.x * 32, r0 = blockIdx.y * 32;
    int tx = threadIdx.x, ty = threadIdx.y;
#pragma unroll
    for (int i = 0; i < 32; i += 8) {
        int r = r0 + ty + i, c = c0 + tx;
        if (r < R && c < Cc) t[ty + i][tx] = src[(size_t)r * Cc + c];
    }
    __syncthreads();
#pragma unroll
    for (int i = 0; i < 32; i += 8) {
        int c = c0 + ty + i, r = r0 + tx;
        if (r < R && c < Cc) dst[(size_t)c * dstride + doff + r] = f2fp8(t[tx][ty + i]);
    }
}

// ---------------- LayerNorm over C=768, write fp8. 4 rows/block, one wave per row.
__global__ __launch_bounds__(256) void ln_rows(const float* __restrict__ x,
                                               const float* __restrict__ w,
                                               u8* __restrict__ xn) {
    int row = blockIdx.x * 4 + (threadIdx.x >> 6);
    int lane = threadIdx.x & 63;
    const f4* xr = (const f4*)(x + (size_t)row * CDIM);
    const f4* wr = (const f4*)w;
    f4 v[3];
    float s = 0.f, s2 = 0.f;
#pragma unroll
    for (int i = 0; i < 3; ++i) {
        v[i] = xr[lane + 64 * i];
#pragma unroll
        for (int j = 0; j < 4; ++j) { s += v[i][j]; s2 += v[i][j] * v[i][j]; }
    }
    s = wsum64(s); s2 = wsum64(s2);
    float mu = s * (1.f / 768.f);
    float var = s2 * (1.f / 768.f) - mu * mu;
    float rs = rsqrtf(var + 1e-5f);
    u32* xo = (u32*)(xn + (size_t)row * CDIM);
#pragma unroll
    for (int i = 0; i < 3; ++i) {
        f4 wv = wr[lane + 64 * i];
        xo[lane + 64 * i] = pk4_fp8((v[i][0] - mu) * rs * wv[0], (v[i][1] - mu) * rs * wv[1],
                                    (v[i][2] - mu) * rs * wv[2], (v[i][3] - mu) * rs * wv[3]);
    }
}

// ---------------- MX-fp8 MFMA GEMM (unit scales), A (MxK) fp8, B^T (NxK) fp8.
// 128x128 block tile, BK=128, 128B LDS rows with 16B-granule XOR swizzle
// (phys chunk = logical ^ (row&7) -> conflict-free b128 reads, round-5-proven).
// 4 waves (2x2); per barrier each wave: 16 ds_read_b128 pairs -> 16
// mfma_scale_f32_16x16x128_f8f6f4 (K=128 in one instruction, 2x fp8 rate).
// MODE 0: proj epilogue (+bqkv; cols<2304 -> fp8 qkv; else fast-gelu -> fp8 A2 ff)
// MODE 1: final epilogue (+bout+bmlp, out = x + gamma*acc, fp32)
template <int MODE>
__global__ __launch_bounds__(256) void gemm_bt(
    const u8* __restrict__ A, const u8* __restrict__ B, int M, int N, int K,
    const float* __restrict__ bias0, const float* __restrict__ bias1,
    const float* __restrict__ xres, const float* __restrict__ gamma,
    u8* __restrict__ oqkv, u8* __restrict__ off, float* __restrict__ ofin) {
    __shared__ __align__(16) u8 As[128 * 128];
    __shared__ __align__(16) u8 Bs[128 * 128];
    const int tid = threadIdx.x;
    const int wid = tid >> 6, lane = tid & 63;
    const int wm = wid >> 1, wn = wid & 1;
    const int quad = lane >> 4, l16 = lane & 15;
    const int m0 = blockIdx.y * 128, n0 = blockIdx.x * 128;

    f4 acc[4][4] = {};

    // staging: each glds16 call = 8 rows x 128B. 4 A-calls + 4 B-calls per wave.
    // lane l: row-in-call = l>>3, phys 16B chunk = l&7; source logical chunk =
    // (l&7) ^ (row&7) with row&7 = l>>3.
    const int rl = lane >> 3;
    const int csw = ((lane & 7) ^ rl) * 16;           // swizzled source byte offset
    const u8* aptr[4]; const u8* bptr[4];
    u8* alds[4]; u8* blds[4];
#pragma unroll
    for (int jj = 0; jj < 4; ++jj) {
        const int r0 = wid * 32 + jj * 8;
        aptr[jj] = A + (size_t)(m0 + r0 + rl) * K + csw;
        bptr[jj] = B + (size_t)(n0 + r0 + rl) * K + csw;
        alds[jj] = As + r0 * 128;
        blds[jj] = Bs + r0 * 128;
    }
    const int swl = l16 & 7;                          // read-side swizzle (16B-chunk units)

    for (int kt = 0; kt < K; kt += 128) {
#pragma unroll
        for (int jj = 0; jj < 4; ++jj) {
            gl_lds16(aptr[jj] + kt, alds[jj]);
            gl_lds16(bptr[jj] + kt, blds[jj]);
        }
        __syncthreads();
        // per-lane A/B frag: 32 k-bytes at k0 = quad*32 -> logical chunks 2q,2q+1
        const int c0 = ((2 * quad) ^ swl) * 16;
        const int c1 = ((2 * quad + 1) ^ swl) * 16;
        i32x8 af[4], bfv[4];
#pragma unroll
        for (int mi = 0; mi < 4; ++mi) {
            const u8* base = As + (wm * 64 + mi * 16 + l16) * 128;
            uint4 lo = *(const uint4*)(base + c0);
            uint4 hi = *(const uint4*)(base + c1);
            af[mi][0] = lo.x; af[mi][1] = lo.y; af[mi][2] = lo.z; af[mi][3] = lo.w;
            af[mi][4] = hi.x; af[mi][5] = hi.y; af[mi][6] = hi.z; af[mi][7] = hi.w;
        }
#pragma unroll
        for (int ni = 0; ni < 4; ++ni) {
            const u8* base = Bs + (wn * 64 + ni * 16 + l16) * 128;
            uint4 lo = *(const uint4*)(base + c0);
            uint4 hi = *(const uint4*)(base + c1);
            bfv[ni][0] = lo.x; bfv[ni][1] = lo.y; bfv[ni][2] = lo.z; bfv[ni][3] = lo.w;
            bfv[ni][4] = hi.x; bfv[ni][5] = hi.y; bfv[ni][6] = hi.z; bfv[ni][7] = hi.w;
        }
#pragma unroll
        for (int mi = 0; mi < 4; ++mi)
#pragma unroll
            for (int ni = 0; ni < 4; ++ni)
                acc[mi][ni] = __builtin_amdgcn_mfma_scale_f32_16x16x128_f8f6f4(
                    af[mi], bfv[ni], acc[mi][ni], 0, 0, 0, 127, 0, 127);
        __syncthreads();
    }

#pragma unroll
    for (int mi = 0; mi < 4; ++mi) {
#pragma unroll
        for (int ni = 0; ni < 4; ++ni) {
            const int col = n0 + wn * 64 + ni * 16 + l16;
            const int rowb = m0 + wm * 64 + mi * 16 + quad * 4;
            if (MODE == 0) {
                const float bc = bias0[col];
#pragma unroll
                for (int r = 0; r < 4; ++r) {
                    float vv = acc[mi][ni][r] + bc;
                    const int m = rowb + r;
                    if (col < 2304) {
                        oqkv[(size_t)m * 2304 + col] = f2fp8(vv);
                    } else {
                        // fast gelu: x*sigmoid(1.5957691216x + 0.0713548162x^3)
                        float u2 = vv * (-1.5957691216f) - 0.0713548162f * vv * vv * vv;
                        float g = vv / (1.f + __expf(u2));
                        off[(size_t)m * KFF + 768 + (col - 2304)] = f2fp8(g);
                    }
                }
            } else {
                const float bc = bias0[col] + bias1[col];
                const float gm = gamma[col];
#pragma unroll
                for (int r = 0; r < 4; ++r) {
                    const int m = rowb + r;
                    float vv = acc[mi][ni][r] + bc;
                    ofin[(size_t)m * CDIM + col] = xres[(size_t)m * CDIM + col] + gm * vv;
                }
            }
        }
    }
}

// ---------------- per-head LN of q and k (64-elem rows), in place on fp8 qkv buffer.
__global__ __launch_bounds__(256) void qk_ln(u8* __restrict__ qkv,
                                             const float* __restrict__ qw,
                                             const float* __restrict__ kw) {
    const size_t m = blockIdx.x;
    const int w = threadIdx.x >> 6, lane = threadIdx.x & 63;
#pragma unroll
    for (int it = 0; it < 6; ++it) {
        const int h = w + 4 * it;   // 0..23
        const int isq = (h < 12);
        const int he = isq ? h : h - 12;
        u8* p = qkv + m * 2304 + (isq ? 0 : 768) + he * 64 + lane;
        const float wt = (isq ? qw : kw)[lane];
        float v = fp8_to_f32(*p);
        float mu = wsum64(v) * (1.f / 64.f);
        float ex2 = wsum64(v * v) * (1.f / 64.f);
        float rs = rsqrtf(ex2 - mu * mu + 1e-5f);
        *p = f2fp8((v - mu) * rs * wt);
    }
}

// ---------------- fp8 MFMA axial attention: block = (b, line j, head he), 4 waves.
// phase 0 = row-j attention, phase 1 = column-j; register-accumulated, one
// fp8 write to A2[tok(b,i,j)]. S^T = K.Q^T (softmax per-lane + 2 quad
// shuffles), P->LDS (u32 packed), O = P.V with V^T built at load.
// All LDS tiles padded to 72B rows -> conflict-free 8B frag reads, no swizzle.
__global__ __launch_bounds__(256) void axial_attn_mfma(const u8* __restrict__ qkv,
                                                       u8* __restrict__ A2) {
    __shared__ __align__(16) u8 Qs[64 * 72];
    __shared__ __align__(16) u8 Ks[64 * 72];
    __shared__ __align__(16) u8 Vt[64 * 72];   // V^T[c][k]
    __shared__ __align__(16) u8 Ps[64 * 72];   // P[q][k]

    const int bx = blockIdx.x;
    const int he = bx % 12;
    const int j = (bx / 12) & 63;
    const int b = bx / (12 * 64);
    const int tid = threadIdx.x;
    const int w = tid >> 6, lane = tid & 63;
    const int l16 = lane & 15, quad = lane >> 4;
    const int qb = w * 16;

    f4 acc_o[4] = {};

    // staging thread mapping: row sr = tid>>2 (0..63), 16B segment sc = (tid&3)*16
    const int sr = tid >> 2;
    const int sc = (tid & 3) * 16;

    for (int phase = 0; phase < 2; ++phase) {
        const size_t tok = (phase == 0) ? (size_t)((b * 64 + j) * 64 + sr)
                                        : (size_t)((b * 64 + sr) * 64 + j);
        const u8* src = qkv + tok * 2304 + he * 64 + sc;
        {
            uint4 qv = *(const uint4*)(src);
            uint4 kv = *(const uint4*)(src + 768);
            *(uint4*)(Qs + sr * 72 + sc) = qv;
            *(uint4*)(Ks + sr * 72 + sc) = kv;
        }
        // V transposed: thread owns (k = sr, c in [sc, sc+16))
        {
            uint4 vv = *(const uint4*)(src + 1536);
            const u8* vb = (const u8*)&vv;
#pragma unroll
            for (int i = 0; i < 16; ++i) Vt[(sc + i) * 72 + sr] = vb[i];
        }
        __syncthreads();

        // ---- S^T tiles: D[m=k-idx][n=q], this wave's q-cols = qb..qb+15
        f4 st[4] = {};
#pragma unroll
        for (int kt = 0; kt < 2; ++kt) {
            const int boff = (kt * 4 + quad) * 8;
            const i64 bq = *(const i64*)(Qs + (qb + l16) * 72 + boff);
#pragma unroll
            for (int mt = 0; mt < 4; ++mt) {
                const i64 ak = *(const i64*)(Ks + (mt * 16 + l16) * 72 + boff);
                st[mt] = __builtin_amdgcn_mfma_f32_16x16x32_fp8_fp8(ak, bq, st[mt], 0, 0, 0);
            }
        }

        // ---- softmax over k (= m axis): per-lane 16 values + cross-quad shuffles
        float sv[16];
        float mx = -1e30f;
#pragma unroll
        for (int mt = 0; mt < 4; ++mt)
#pragma unroll
            for (int r = 0; r < 4; ++r) {
                const float s = st[mt][r] * 0.125f;
                sv[mt * 4 + r] = s;
                mx = fmaxf(mx, s);
            }
        mx = fmaxf(mx, __shfl_xor(mx, 16, 64));
        mx = fmaxf(mx, __shfl_xor(mx, 32, 64));
        float sm = 0.f;
#pragma unroll
        for (int i = 0; i < 16; ++i) { sv[i] = __expf(sv[i] - mx); sm += sv[i]; }
        sm += __shfl_xor(sm, 16, 64);
        sm += __shfl_xor(sm, 32, 64);
        const float inv = 1.f / sm;

        // ---- write P[q][k] (transpose out of C-layout), packed u32 stores
#pragma unroll
        for (int mt = 0; mt < 4; ++mt) {
            const int kbase = mt * 16 + quad * 4;
            *(u32*)(Ps + (qb + l16) * 72 + kbase) =
                pk4_fp8(sv[mt * 4] * inv, sv[mt * 4 + 1] * inv,
                        sv[mt * 4 + 2] * inv, sv[mt * 4 + 3] * inv);
        }
        __syncthreads();

        // ---- O += P.V : m-tile = this wave's q rows, n-tiles over c
#pragma unroll
        for (int kt = 0; kt < 2; ++kt) {
            const int boff = (kt * 4 + quad) * 8;
            const i64 ap = *(const i64*)(Ps + (qb + l16) * 72 + boff);
#pragma unroll
            for (int nt = 0; nt < 4; ++nt) {
                const i64 bv = *(const i64*)(Vt + (nt * 16 + l16) * 72 + boff);
                acc_o[nt] = __builtin_amdgcn_mfma_f32_16x16x32_fp8_fp8(ap, bv, acc_o[nt], 0, 0, 0);
            }
        }
        __syncthreads();   // protect tiles before next phase reload
    }

    // ---- store: q = qb + quad*4 + r, c = nt*16 + l16
#pragma unroll
    for (int nt = 0; nt < 4; ++nt)
#pragma unroll
        for (int r = 0; r < 4; ++r) {
            const int q = qb + quad * 4 + r;
            const int c = nt * 16 + l16;
            A2[((size_t)((b * 64 + q) * 64 + j)) * KFF + he * 64 + c] = f2fp8(acc_o[nt][r]);
        }
}

extern "C" void kernel_launch(void* const* d_in, const int* in_sizes, int n_in,
                              void* d_out, int out_size, void* d_ws, size_t ws_size,
                              hipStream_t stream) {
    const float* x = (const float*)d_in[0];
    const float* normw = (const float*)d_in[1];
    const float* Wqkv = (const float*)d_in[2];
    const float* bqkv = (const float*)d_in[3];
    const float* qnw = (const float*)d_in[4];
    const float* knw = (const float*)d_in[5];
    const float* Wout = (const float*)d_in[6];
    const float* bout = (const float*)d_in[7];
    const float* Wmlp = (const float*)d_in[8];
    const float* bmlp = (const float*)d_in[9];
    const float* gamma = (const float*)d_in[10];
    float* out = (float*)d_out;

    char* ws = (char*)d_ws;
    u8* xn = (u8*)ws;    ws += (size_t)NTOK * CDIM;
    u8* WqkvT = (u8*)ws; ws += (size_t)NPROJ * CDIM;
    u8* BT2 = (u8*)ws;   ws += (size_t)CDIM * KFF;
    u8* qkv = (u8*)ws;   ws += (size_t)NTOK * 2304;
    u8* A2 = (u8*)ws;    ws += (size_t)NTOK * KFF;

    // weights -> B^T fp8
    transpose_cast<<<dim3(NPROJ / 32, CDIM / 32), dim3(32, 8), 0, stream>>>(Wqkv, WqkvT, CDIM, NPROJ, CDIM, 0);
    transpose_cast<<<dim3(CDIM / 32, CDIM / 32), dim3(32, 8), 0, stream>>>(Wout, BT2, CDIM, CDIM, KFF, 0);
    transpose_cast<<<dim3(CDIM / 32, 3072 / 32), dim3(32, 8), 0, stream>>>(Wmlp, BT2, 3072, CDIM, KFF, 768);
    // LN(x) -> fp8
    ln_rows<<<NTOK / 4, 256, 0, stream>>>(x, normw, xn);
    // proj GEMM: q,k,v -> qkv buffer; gelu(ff) -> A2[:, 768:3840]
    gemm_bt<0><<<dim3(NPROJ / 128, NTOK / 128), 256, 0, stream>>>(
        xn, WqkvT, NTOK, NPROJ, CDIM, bqkv, nullptr, nullptr, nullptr, qkv, A2, nullptr);
    // per-head LN of q,k in place
    qk_ln<<<NTOK, 256, 0, stream>>>(qkv, qnw, knw);
    // both axial attentions -> A2[:, 0:768]
    axial_attn_mfma<<<3072, 256, 0, stream>>>(qkv, A2);
    // final fused GEMM: out = x + gamma * (A2 @ [WoutT|WmlpT] + bout + bmlp)
    gemm_bt<1><<<dim3(CDIM / 128, NTOK / 128), 256, 0, stream>>>(
        A2, BT2, NTOK, CDIM, KFF, bout, bmlp, x, gamma, nullptr, nullptr, out);
}